// Round 1
// baseline (1645.470 us; speedup 1.0000x reference)
//
#include <hip/hip_runtime.h>
#include <math.h>

#define E 192
#define DI 384
#define S 16
#define R 12
#define DEPTH 4
#define P 400
#define NC 20
#define BATCH 32
#define L 401
#define NTOK (BATCH * L)   // 12832
#define CH 64
#define NCH 7              // ceil(401/64)

__device__ __forceinline__ float siluf(float x) {
    return x / (1.f + __expf(-x));
}
__device__ __forceinline__ float softplusf(float x) {
    return (x > 20.f) ? x : log1pf(__expf(x));
}

// ---------------------------------------------------------------------------
// K0: patch embed + pos + depthwise conv3 + cls token  -> resid[b,l,e]
// ---------------------------------------------------------------------------
__global__ void k_embed(const float* __restrict__ imgs, const float* __restrict__ patch_w,
                        const float* __restrict__ patch_b, const float* __restrict__ cls_token,
                        const float* __restrict__ pos_embed, const float* __restrict__ cnn_w,
                        const float* __restrict__ cnn_b, float* __restrict__ resid) {
    int idx = blockIdx.x * blockDim.x + threadIdx.x;
    if (idx >= NTOK * E) return;
    int e = idx % E;
    int bl = idx / E;
    int l = bl % L;
    int b = bl / L;
    float out;
    if (l == P) {
        out = cls_token[e] + pos_embed[(size_t)P * E + e];
    } else {
        float w0 = patch_w[e * 4 + 0], w1 = patch_w[e * 4 + 1];
        float w2 = patch_w[e * 4 + 2], w3 = patch_w[e * 4 + 3];
        float pb = patch_b[e];
        const float* ib = imgs + (size_t)b * 1600;
        // xe(ll) = patch embed + pos at position ll
        auto xe = [&](int ll) -> float {
            const float* ip = ib + ll * 4;
            return ip[0] * w0 + ip[1] * w1 + ip[2] * w2 + ip[3] * w3 + pb +
                   pos_embed[(size_t)ll * E + e];
        };
        float c0 = cnn_w[e * 3 + 0], c1 = cnn_w[e * 3 + 1], c2 = cnn_w[e * 3 + 2];
        float acc = cnn_b[e] + xe(l) * c1;
        if (l > 0) acc += xe(l - 1) * c0;
        if (l < P - 1) acc += xe(l + 1) * c2;
        out = acc;
    }
    resid[idx] = out;
}

// ---------------------------------------------------------------------------
// K1: (optional resid += hidden) then hn = rmsnorm(resid) * w. One wave/token.
// ---------------------------------------------------------------------------
template <bool ADD>
__global__ void k_rmsnorm(const float* __restrict__ hidden, float* __restrict__ resid,
                          float* __restrict__ hn, const float* __restrict__ w) {
    int wave = blockIdx.x * (blockDim.x >> 6) + (threadIdx.x >> 6);
    int lane = threadIdx.x & 63;
    if (wave >= NTOK) return;
    size_t base = (size_t)wave * E;
    float v[3];
    float ss = 0.f;
#pragma unroll
    for (int j = 0; j < 3; j++) {
        int e = lane + j * 64;
        float r = resid[base + e];
        if (ADD) {
            r += hidden[base + e];
            resid[base + e] = r;
        }
        v[j] = r;
        ss += r * r;
    }
#pragma unroll
    for (int off = 32; off > 0; off >>= 1) ss += __shfl_xor(ss, off, 64);
    float scale = rsqrtf(ss * (1.f / (float)E) + 1e-5f);
#pragma unroll
    for (int j = 0; j < 3; j++) {
        int e = lane + j * 64;
        hn[base + e] = v[j] * scale * w[e];
    }
}

// ---------------------------------------------------------------------------
// K2: generic f32 GEMM  C[M,N] = A[M,lda(cols 0..K-1)] * W[N,K]^T (+bias)(+act)
// 64x64 tile, 256 threads, 4x4 microtile. act: 0=none, 1=softplus
// ---------------------------------------------------------------------------
__global__ __launch_bounds__(256) void k_gemm(const float* __restrict__ A, int lda,
                                              const float* __restrict__ W,
                                              const float* __restrict__ bias,
                                              float* __restrict__ C, int M, int N, int K,
                                              int act) {
    __shared__ float As[16][68];
    __shared__ float Bs[16][68];
    int tid = threadIdx.x;
    int m0 = blockIdx.y * 64, n0 = blockIdx.x * 64;
    int tx = tid & 15, ty = tid >> 4;
    int lr = tid >> 2, lk = (tid & 3) * 4;
    float acc[4][4] = {};
    for (int k0 = 0; k0 < K; k0 += 16) {
        {
            int m = m0 + lr;
            int n = n0 + lr;
#pragma unroll
            for (int j = 0; j < 4; j++) {
                int k = k0 + lk + j;
                As[lk + j][lr] = (m < M && k < K) ? A[(size_t)m * lda + k] : 0.f;
                Bs[lk + j][lr] = (n < N && k < K) ? W[(size_t)n * K + k] : 0.f;
            }
        }
        __syncthreads();
#pragma unroll
        for (int k = 0; k < 16; k++) {
            float a[4], b[4];
#pragma unroll
            for (int j = 0; j < 4; j++) a[j] = As[k][ty * 4 + j];
#pragma unroll
            for (int j = 0; j < 4; j++) b[j] = Bs[k][tx * 4 + j];
#pragma unroll
            for (int i = 0; i < 4; i++)
#pragma unroll
                for (int j = 0; j < 4; j++) acc[i][j] += a[i] * b[j];
        }
        __syncthreads();
    }
#pragma unroll
    for (int i = 0; i < 4; i++) {
        int m = m0 + ty * 4 + i;
        if (m >= M) continue;
#pragma unroll
        for (int j = 0; j < 4; j++) {
            int n = n0 + tx * 4 + j;
            if (n >= N) continue;
            float v = acc[i][j];
            if (bias) v += bias[n];
            if (act == 1) v = softplusf(v);
            C[(size_t)m * N + n] = v;
        }
    }
}

// ---------------------------------------------------------------------------
// K3: causal depthwise conv4 + SiLU over xm = xz[..., :DI]  -> xc
// ---------------------------------------------------------------------------
__global__ void k_conv(const float* __restrict__ xz, const float* __restrict__ cw,
                       const float* __restrict__ cb, float* __restrict__ xc) {
    int idx = blockIdx.x * blockDim.x + threadIdx.x;
    if (idx >= NTOK * DI) return;
    int d = idx % DI;
    int bl = idx / DI;
    int l = bl % L;
    int b = bl / L;
    const float* base = xz + (size_t)b * L * (2 * DI) + d;
    float acc = cb[d];
#pragma unroll
    for (int k = 0; k < 4; k++) {
        int ll = l - 3 + k;
        if (ll >= 0) acc += base[(size_t)ll * (2 * DI)] * cw[d * 4 + k];
    }
    xc[idx] = siluf(acc);
}

// ---------------------------------------------------------------------------
// K4a: chunk-local scan: h starts at 0, store h_end and sum(dt) per chunk.
// grid (NCH, BATCH) x 384 threads
// ---------------------------------------------------------------------------
__global__ void k_scanA(const float* __restrict__ dt, const float* __restrict__ xc,
                        const float* __restrict__ xdb, const float* __restrict__ A_log,
                        float* __restrict__ hend, float* __restrict__ dtsum) {
    int d = threadIdx.x;
    int ch = blockIdx.x;
    int b = blockIdx.y;
    int t0 = ch * CH;
    int t1 = min(t0 + CH, L);
    float a[S];
#pragma unroll
    for (int n = 0; n < S; n++) a[n] = -__expf(A_log[d * S + n]);
    float h[S] = {};
    float dts = 0.f;
    for (int t = t0; t < t1; t++) {
        size_t tok = (size_t)b * L + t;
        float dtv = dt[tok * DI + d];
        float u = xc[tok * DI + d];
        dts += dtv;
        float dtu = dtv * u;
        const float* bv = xdb + tok * 44 + R;
#pragma unroll
        for (int n = 0; n < S; n++) {
            float dA = __expf(dtv * a[n]);
            h[n] = dA * h[n] + dtu * bv[n];
        }
    }
    size_t o = (((size_t)b * NCH + ch) * DI + d) * S;
#pragma unroll
    for (int n = 0; n < S; n++) hend[o + n] = h[n];
    dtsum[((size_t)b * NCH + ch) * DI + d] = dts;
}

// ---------------------------------------------------------------------------
// K4b: combine chunk prefixes serially (7 chunks). grid-stride over B*DI.
// ---------------------------------------------------------------------------
__global__ void k_scanB(const float* __restrict__ hend, const float* __restrict__ dtsum,
                        const float* __restrict__ A_log, float* __restrict__ hinit) {
    int idx = blockIdx.x * blockDim.x + threadIdx.x;
    if (idx >= BATCH * DI) return;
    int d = idx % DI;
    int b = idx / DI;
    float a[S];
#pragma unroll
    for (int n = 0; n < S; n++) a[n] = -__expf(A_log[d * S + n]);
    float h[S] = {};
    for (int ch = 0; ch < NCH; ch++) {
        size_t o = (((size_t)b * NCH + ch) * DI + d) * S;
#pragma unroll
        for (int n = 0; n < S; n++) hinit[o + n] = h[n];
        float dts = dtsum[((size_t)b * NCH + ch) * DI + d];
#pragma unroll
        for (int n = 0; n < S; n++) h[n] = __expf(dts * a[n]) * h[n] + hend[o + n];
    }
}

// ---------------------------------------------------------------------------
// K4c: replay with correct h_init, compute y, fuse D-skip + SiLU(z) gate.
// Writes gated y over the dt buffer (safe: dt[t] read before write at step t).
// ---------------------------------------------------------------------------
__global__ void k_scanC(const float* __restrict__ xz, const float* __restrict__ xc,
                        const float* __restrict__ xdb, const float* __restrict__ A_log,
                        const float* __restrict__ Dskip, const float* __restrict__ hinit,
                        float* __restrict__ dty) {
    int d = threadIdx.x;
    int ch = blockIdx.x;
    int b = blockIdx.y;
    int t0 = ch * CH;
    int t1 = min(t0 + CH, L);
    float a[S];
#pragma unroll
    for (int n = 0; n < S; n++) a[n] = -__expf(A_log[d * S + n]);
    float h[S];
    size_t o = (((size_t)b * NCH + ch) * DI + d) * S;
#pragma unroll
    for (int n = 0; n < S; n++) h[n] = hinit[o + n];
    float dsk = Dskip[d];
    for (int t = t0; t < t1; t++) {
        size_t tok = (size_t)b * L + t;
        float dtv = dty[tok * DI + d];
        float u = xc[tok * DI + d];
        float z = xz[tok * (2 * DI) + DI + d];
        float dtu = dtv * u;
        const float* bv = xdb + tok * 44 + R;
        const float* cv = xdb + tok * 44 + R + S;
        float y = 0.f;
#pragma unroll
        for (int n = 0; n < S; n++) {
            float dA = __expf(dtv * a[n]);
            h[n] = dA * h[n] + dtu * bv[n];
            y += h[n] * cv[n];
        }
        y += u * dsk;
        dty[tok * DI + d] = y * siluf(z);
    }
}

// ---------------------------------------------------------------------------
// K5: final rmsnorm of token 400 of (resid+hidden), then head matmul -> out
// one block (64 threads) per batch element
// ---------------------------------------------------------------------------
__global__ void k_head(const float* __restrict__ resid, const float* __restrict__ hidden,
                       const float* __restrict__ norm_f_w, const float* __restrict__ head_w,
                       const float* __restrict__ head_b, float* __restrict__ out) {
    __shared__ float v[E];
    int b = blockIdx.x;
    int lane = threadIdx.x;
    size_t base = ((size_t)b * L + P) * E;
    float loc[3];
    float ss = 0.f;
#pragma unroll
    for (int j = 0; j < 3; j++) {
        int e = lane + j * 64;
        float x = resid[base + e] + hidden[base + e];
        loc[j] = x;
        ss += x * x;
    }
#pragma unroll
    for (int off = 32; off > 0; off >>= 1) ss += __shfl_xor(ss, off, 64);
    float scale = rsqrtf(ss * (1.f / (float)E) + 1e-5f);
#pragma unroll
    for (int j = 0; j < 3; j++) {
        int e = lane + j * 64;
        v[e] = loc[j] * scale * norm_f_w[e];
    }
    __syncthreads();
    if (lane < NC) {
        float acc = head_b[lane];
        for (int e = 0; e < E; e++) acc += v[e] * head_w[lane * E + e];
        out[b * NC + lane] = acc;
    }
}

// ---------------------------------------------------------------------------
extern "C" void kernel_launch(void* const* d_in, const int* in_sizes, int n_in,
                              void* d_out, int out_size, void* d_ws, size_t ws_size,
                              hipStream_t stream) {
    const float* imgs      = (const float*)d_in[0];
    const float* patch_w   = (const float*)d_in[1];
    const float* patch_b   = (const float*)d_in[2];
    const float* cls_token = (const float*)d_in[3];
    const float* pos_embed = (const float*)d_in[4];
    const float* cnn_w     = (const float*)d_in[5];
    const float* cnn_b     = (const float*)d_in[6];
    const float* norm_w    = (const float*)d_in[7];
    const float* in_proj_w = (const float*)d_in[8];
    const float* conv_w    = (const float*)d_in[9];
    const float* conv_b    = (const float*)d_in[10];
    const float* x_proj_w  = (const float*)d_in[11];
    const float* dt_proj_w = (const float*)d_in[12];
    const float* dt_proj_b = (const float*)d_in[13];
    const float* A_log     = (const float*)d_in[14];
    const float* Dskip     = (const float*)d_in[15];
    const float* out_proj_w= (const float*)d_in[16];
    const float* norm_f_w  = (const float*)d_in[17];
    const float* head_w    = (const float*)d_in[18];
    const float* head_b    = (const float*)d_in[19];

    float* ws = (float*)d_ws;
    size_t off = 0;
    float* resid  = ws + off; off += (size_t)NTOK * E;        // 2,463,744
    float* hn     = ws + off; off += (size_t)NTOK * E;
    float* hidden = ws + off; off += (size_t)NTOK * E;
    float* xz     = ws + off; off += (size_t)NTOK * 2 * DI;   // 9,854,976
    float* xc     = ws + off; off += (size_t)NTOK * DI;
    float* xdb    = ws + off; off += (size_t)NTOK * 44;
    float* dt     = ws + off; off += (size_t)NTOK * DI;       // also reused as gated-y
    float* hend   = ws + off; off += (size_t)BATCH * NCH * DI * S;
    float* hinit  = ws + off; off += (size_t)BATCH * NCH * DI * S;
    float* dtsum  = ws + off; off += (size_t)BATCH * NCH * DI;

    // K0: embed
    k_embed<<<(NTOK * E) / 256, 256, 0, stream>>>(imgs, patch_w, patch_b, cls_token,
                                                  pos_embed, cnn_w, cnn_b, resid);

    for (int i = 0; i < DEPTH; i++) {
        // rmsnorm (+ residual accumulate after layer 0)
        if (i == 0)
            k_rmsnorm<false><<<NTOK / 4, 256, 0, stream>>>(hidden, resid, hn, norm_w + i * E);
        else
            k_rmsnorm<true><<<NTOK / 4, 256, 0, stream>>>(hidden, resid, hn, norm_w + i * E);

        // in_proj: [NTOK,192] x [768,192]^T -> xz [NTOK,768]
        {
            dim3 g((2 * DI + 63) / 64, (NTOK + 63) / 64);
            k_gemm<<<g, 256, 0, stream>>>(hn, E, in_proj_w + (size_t)i * 2 * DI * E, nullptr,
                                          xz, NTOK, 2 * DI, E, 0);
        }
        // causal conv4 + silu
        k_conv<<<(NTOK * DI) / 256, 256, 0, stream>>>(xz, conv_w + (size_t)i * DI * 4,
                                                      conv_b + (size_t)i * DI, xc);
        // x_proj: [NTOK,384] x [44,384]^T -> xdb [NTOK,44]
        {
            dim3 g(1, (NTOK + 63) / 64);
            k_gemm<<<g, 256, 0, stream>>>(xc, DI, x_proj_w + (size_t)i * 44 * DI, nullptr,
                                          xdb, NTOK, 44, DI, 0);
        }
        // dt_proj: [NTOK,12] x [384,12]^T + b -> softplus -> dt [NTOK,384]
        {
            dim3 g((DI + 63) / 64, (NTOK + 63) / 64);
            k_gemm<<<g, 256, 0, stream>>>(xdb, 44, dt_proj_w + (size_t)i * DI * R,
                                          dt_proj_b + (size_t)i * DI, dt, NTOK, DI, R, 1);
        }
        // chunked scan
        {
            dim3 g(NCH, BATCH);
            k_scanA<<<g, DI, 0, stream>>>(dt, xc, xdb, A_log + (size_t)i * DI * S, hend, dtsum);
            k_scanB<<<(BATCH * DI + 255) / 256, 256, 0, stream>>>(
                hend, dtsum, A_log + (size_t)i * DI * S, hinit);
            k_scanC<<<g, DI, 0, stream>>>(xz, xc, xdb, A_log + (size_t)i * DI * S,
                                          Dskip + (size_t)i * DI, hinit, dt);
        }
        // out_proj: [NTOK,384] x [192,384]^T -> hidden [NTOK,192]
        {
            dim3 g((E + 63) / 64, (NTOK + 63) / 64);
            k_gemm<<<g, 256, 0, stream>>>(dt, DI, out_proj_w + (size_t)i * E * DI, nullptr,
                                          hidden, NTOK, E, DI, 0);
        }
    }

    // final norm of last token + head
    k_head<<<BATCH, 64, 0, stream>>>(resid, hidden, norm_f_w, head_w, head_b, (float*)d_out);
}

// Round 3
// 864.278 us; speedup vs baseline: 1.9039x; 1.9039x over previous
//
#include <hip/hip_runtime.h>
#include <math.h>

#define E 192
#define DI 384
#define S 16
#define R 12
#define DEPTH 4
#define P 400
#define NC 20
#define BATCH 32
#define L 401
#define NTOK (BATCH * L)   // 12832
#define CH 64
#define NCH 7              // ceil(401/64)

using short8 = __attribute__((ext_vector_type(8))) short;
using float4v = __attribute__((ext_vector_type(4))) float;

__device__ __forceinline__ float siluf(float x) {
    return x / (1.f + __expf(-x));
}
__device__ __forceinline__ float softplusf(float x) {
    return (x > 20.f) ? x : log1pf(__expf(x));
}
// f32 -> bf16 with round-to-nearest-even (bit-level; no __hip_bfloat16 dep)
__device__ __forceinline__ unsigned short f2bf(float x) {
    unsigned int u = __float_as_uint(x);
    unsigned int r = 0x7fffu + ((u >> 16) & 1u);
    return (unsigned short)((u + r) >> 16);
}

// ---------------------------------------------------------------------------
// K0: patch embed + pos + depthwise conv3 + cls token  -> resid[b,l,e]
// ---------------------------------------------------------------------------
__global__ void k_embed(const float* __restrict__ imgs, const float* __restrict__ patch_w,
                        const float* __restrict__ patch_b, const float* __restrict__ cls_token,
                        const float* __restrict__ pos_embed, const float* __restrict__ cnn_w,
                        const float* __restrict__ cnn_b, float* __restrict__ resid) {
    int idx = blockIdx.x * blockDim.x + threadIdx.x;
    if (idx >= NTOK * E) return;
    int e = idx % E;
    int bl = idx / E;
    int l = bl % L;
    int b = bl / L;
    float out;
    if (l == P) {
        out = cls_token[e] + pos_embed[(size_t)P * E + e];
    } else {
        float w0 = patch_w[e * 4 + 0], w1 = patch_w[e * 4 + 1];
        float w2 = patch_w[e * 4 + 2], w3 = patch_w[e * 4 + 3];
        float pb = patch_b[e];
        const float* ib = imgs + (size_t)b * 1600;
        auto xe = [&](int ll) -> float {
            const float* ip = ib + ll * 4;
            return ip[0] * w0 + ip[1] * w1 + ip[2] * w2 + ip[3] * w3 + pb +
                   pos_embed[(size_t)ll * E + e];
        };
        float c0 = cnn_w[e * 3 + 0], c1 = cnn_w[e * 3 + 1], c2 = cnn_w[e * 3 + 2];
        float acc = cnn_b[e] + xe(l) * c1;
        if (l > 0) acc += xe(l - 1) * c0;
        if (l < P - 1) acc += xe(l + 1) * c2;
        out = acc;
    }
    resid[idx] = out;
}

// ---------------------------------------------------------------------------
// K1: (optional resid += hidden) then hn = rmsnorm(resid)*w -> bf16
// ---------------------------------------------------------------------------
template <bool ADD>
__global__ void k_rmsnorm(const float* __restrict__ hidden, float* __restrict__ resid,
                          unsigned short* __restrict__ hn, const float* __restrict__ w) {
    int wave = blockIdx.x * (blockDim.x >> 6) + (threadIdx.x >> 6);
    int lane = threadIdx.x & 63;
    if (wave >= NTOK) return;
    size_t base = (size_t)wave * E;
    float v[3];
    float ss = 0.f;
#pragma unroll
    for (int j = 0; j < 3; j++) {
        int e = lane + j * 64;
        float r = resid[base + e];
        if (ADD) {
            r += hidden[base + e];
            resid[base + e] = r;
        }
        v[j] = r;
        ss += r * r;
    }
#pragma unroll
    for (int off = 32; off > 0; off >>= 1) ss += __shfl_xor(ss, off, 64);
    float scale = rsqrtf(ss * (1.f / (float)E) + 1e-5f);
#pragma unroll
    for (int j = 0; j < 3; j++) {
        int e = lane + j * 64;
        hn[base + e] = f2bf(v[j] * scale * w[e]);
    }
}

// ---------------------------------------------------------------------------
// K_cvt: f32 -> bf16 (weights, once per launch)
// ---------------------------------------------------------------------------
__global__ void k_cvt(const float* __restrict__ src, unsigned short* __restrict__ dst, int n) {
    int idx = blockIdx.x * blockDim.x + threadIdx.x;
    if (idx < n) dst[idx] = f2bf(src[idx]);
}

// ---------------------------------------------------------------------------
// K2: bf16 MFMA GEMM  C[M,N](f32) = A[M,K](bf16) * W[N,K](bf16)^T
// block 256 (4 waves), tile 128x64, BK=64. Waves 2x2 over (M,N); each wave:
// 4 m-tiles x 2 n-tiles of 16x16 mfma.
// ---------------------------------------------------------------------------
__global__ __launch_bounds__(256) void k_gemm_bf16(const unsigned short* __restrict__ A,
                                                   const unsigned short* __restrict__ W,
                                                   float* __restrict__ C, int M, int N, int K) {
    constexpr int BM = 128, BN = 64, BK = 64, PADK = BK + 8;
    __shared__ unsigned short As[BM][PADK];
    __shared__ unsigned short Bs[BN][PADK];
    int tid = threadIdx.x;
    int m0 = blockIdx.y * BM, n0 = blockIdx.x * BN;
    int wave = tid >> 6, lane = tid & 63;
    int row16 = lane & 15, quad = lane >> 4;
    int wm0 = (wave >> 1) * 64, wn0 = (wave & 1) * 32;

    float4v acc[4][2];
#pragma unroll
    for (int i = 0; i < 4; i++)
#pragma unroll
        for (int j = 0; j < 2; j++) acc[i][j] = (float4v){0.f, 0.f, 0.f, 0.f};

    for (int k0 = 0; k0 < K; k0 += BK) {
        // stage A: 128x64 = 8192 elems, 4 passes of 256 thr x 8
#pragma unroll
        for (int p = 0; p < 4; p++) {
            int idx = (p * 256 + tid) * 8;
            int row = idx / BK, col = idx % BK;
            int gm = m0 + row;
            short8 v;
            if (gm < M)
                v = *(const short8*)&A[(size_t)gm * K + k0 + col];
            else
                v = (short8)0;
            *(short8*)&As[row][col] = v;
        }
        // stage B: 64x64 = 4096 elems, 2 passes
#pragma unroll
        for (int p = 0; p < 2; p++) {
            int idx = (p * 256 + tid) * 8;
            int row = idx / BK, col = idx % BK;
            int gn = n0 + row;
            short8 v;
            if (gn < N)
                v = *(const short8*)&W[(size_t)gn * K + k0 + col];
            else
                v = (short8)0;
            *(short8*)&Bs[row][col] = v;
        }
        __syncthreads();
#pragma unroll
        for (int kk = 0; kk < BK; kk += 32) {
            int koff = kk + quad * 8;
            short8 af[4], bfr[2];
#pragma unroll
            for (int i = 0; i < 4; i++)
                af[i] = *(const short8*)&As[wm0 + i * 16 + row16][koff];
#pragma unroll
            for (int j = 0; j < 2; j++)
                bfr[j] = *(const short8*)&Bs[wn0 + j * 16 + row16][koff];
#pragma unroll
            for (int i = 0; i < 4; i++)
#pragma unroll
                for (int j = 0; j < 2; j++)
                    acc[i][j] = __builtin_amdgcn_mfma_f32_16x16x32_bf16(af[i], bfr[j],
                                                                        acc[i][j], 0, 0, 0);
        }
        __syncthreads();
    }
    // write out: D layout row=quad*4+r, col=row16
#pragma unroll
    for (int i = 0; i < 4; i++) {
#pragma unroll
        for (int j = 0; j < 2; j++) {
#pragma unroll
            for (int r = 0; r < 4; r++) {
                int m = m0 + wm0 + i * 16 + quad * 4 + r;
                int n = n0 + wn0 + j * 16 + row16;
                if (m < M && n < N) C[(size_t)m * N + n] = acc[i][j][r];
            }
        }
    }
}

// ---------------------------------------------------------------------------
// K3: causal depthwise conv4 + SiLU over xm = xz[..., :DI] -> xc (f32 + bf16)
// ---------------------------------------------------------------------------
__global__ void k_conv(const float* __restrict__ xz, const float* __restrict__ cw,
                       const float* __restrict__ cb, float* __restrict__ xc,
                       unsigned short* __restrict__ xc_bf) {
    int idx = blockIdx.x * blockDim.x + threadIdx.x;
    if (idx >= NTOK * DI) return;
    int d = idx % DI;
    int bl = idx / DI;
    int l = bl % L;
    int b = bl / L;
    const float* base = xz + (size_t)b * L * (2 * DI) + d;
    float acc = cb[d];
#pragma unroll
    for (int k = 0; k < 4; k++) {
        int ll = l - 3 + k;
        if (ll >= 0) acc += base[(size_t)ll * (2 * DI)] * cw[d * 4 + k];
    }
    float v = siluf(acc);
    xc[idx] = v;
    xc_bf[idx] = f2bf(v);
}

// ---------------------------------------------------------------------------
// K_dt: dt = softplus(xdb[:, :12] @ dtw^T + dtb), elementwise over NTOK*DI
// ---------------------------------------------------------------------------
__global__ void k_dtproj(const float* __restrict__ xdb, const float* __restrict__ dtw,
                         const float* __restrict__ dtb, float* __restrict__ dt) {
    int idx = blockIdx.x * blockDim.x + threadIdx.x;
    if (idx >= NTOK * DI) return;
    int d = idx % DI;
    int tok = idx / DI;
    const float* xr = xdb + (size_t)tok * 44;
    const float* wr = dtw + (size_t)d * R;
    float acc = dtb[d];
#pragma unroll
    for (int r = 0; r < R; r++) acc += xr[r] * wr[r];
    dt[idx] = softplusf(acc);
}

// ---------------------------------------------------------------------------
// K4a: chunk-local scan: h starts at 0, store h_end and sum(dt) per chunk.
// ---------------------------------------------------------------------------
__global__ void k_scanA(const float* __restrict__ dt, const float* __restrict__ xc,
                        const float* __restrict__ xdb, const float* __restrict__ A_log,
                        float* __restrict__ hend, float* __restrict__ dtsum) {
    int d = threadIdx.x;
    int ch = blockIdx.x;
    int b = blockIdx.y;
    int t0 = ch * CH;
    int t1 = min(t0 + CH, L);
    float a[S];
#pragma unroll
    for (int n = 0; n < S; n++) a[n] = -__expf(A_log[d * S + n]);
    float h[S] = {};
    float dts = 0.f;
    for (int t = t0; t < t1; t++) {
        size_t tok = (size_t)b * L + t;
        float dtv = dt[tok * DI + d];
        float u = xc[tok * DI + d];
        dts += dtv;
        float dtu = dtv * u;
        const float* bv = xdb + tok * 44 + R;
#pragma unroll
        for (int n = 0; n < S; n++) {
            float dA = __expf(dtv * a[n]);
            h[n] = dA * h[n] + dtu * bv[n];
        }
    }
    size_t o = (((size_t)b * NCH + ch) * DI + d) * S;
#pragma unroll
    for (int n = 0; n < S; n++) hend[o + n] = h[n];
    dtsum[((size_t)b * NCH + ch) * DI + d] = dts;
}

// ---------------------------------------------------------------------------
// K4b: combine chunk prefixes serially (7 chunks).
// ---------------------------------------------------------------------------
__global__ void k_scanB(const float* __restrict__ hend, const float* __restrict__ dtsum,
                        const float* __restrict__ A_log, float* __restrict__ hinit) {
    int idx = blockIdx.x * blockDim.x + threadIdx.x;
    if (idx >= BATCH * DI) return;
    int d = idx % DI;
    int b = idx / DI;
    float a[S];
#pragma unroll
    for (int n = 0; n < S; n++) a[n] = -__expf(A_log[d * S + n]);
    float h[S] = {};
    for (int ch = 0; ch < NCH; ch++) {
        size_t o = (((size_t)b * NCH + ch) * DI + d) * S;
#pragma unroll
        for (int n = 0; n < S; n++) hinit[o + n] = h[n];
        float dts = dtsum[((size_t)b * NCH + ch) * DI + d];
#pragma unroll
        for (int n = 0; n < S; n++) h[n] = __expf(dts * a[n]) * h[n] + hend[o + n];
    }
}

// ---------------------------------------------------------------------------
// K4c: replay with correct h_init, compute y, fuse D-skip + SiLU(z) gate -> bf16
// ---------------------------------------------------------------------------
__global__ void k_scanC(const float* __restrict__ xz, const float* __restrict__ xc,
                        const float* __restrict__ xdb, const float* __restrict__ A_log,
                        const float* __restrict__ Dskip, const float* __restrict__ hinit,
                        const float* __restrict__ dt, unsigned short* __restrict__ y_bf) {
    int d = threadIdx.x;
    int ch = blockIdx.x;
    int b = blockIdx.y;
    int t0 = ch * CH;
    int t1 = min(t0 + CH, L);
    float a[S];
#pragma unroll
    for (int n = 0; n < S; n++) a[n] = -__expf(A_log[d * S + n]);
    float h[S];
    size_t o = (((size_t)b * NCH + ch) * DI + d) * S;
#pragma unroll
    for (int n = 0; n < S; n++) h[n] = hinit[o + n];
    float dsk = Dskip[d];
    for (int t = t0; t < t1; t++) {
        size_t tok = (size_t)b * L + t;
        float dtv = dt[tok * DI + d];
        float u = xc[tok * DI + d];
        float z = xz[tok * (2 * DI) + DI + d];
        float dtu = dtv * u;
        const float* bv = xdb + tok * 44 + R;
        const float* cv = xdb + tok * 44 + R + S;
        float y = 0.f;
#pragma unroll
        for (int n = 0; n < S; n++) {
            float dA = __expf(dtv * a[n]);
            h[n] = dA * h[n] + dtu * bv[n];
            y += h[n] * cv[n];
        }
        y += u * dsk;
        y_bf[tok * DI + d] = f2bf(y * siluf(z));
    }
}

// ---------------------------------------------------------------------------
// K5: final rmsnorm of token 400 of (resid+hidden), then head matmul -> out
// ---------------------------------------------------------------------------
__global__ void k_head(const float* __restrict__ resid, const float* __restrict__ hidden,
                       const float* __restrict__ norm_f_w, const float* __restrict__ head_w,
                       const float* __restrict__ head_b, float* __restrict__ out) {
    __shared__ float v[E];
    int b = blockIdx.x;
    int lane = threadIdx.x;
    size_t base = ((size_t)b * L + P) * E;
    float loc[3];
    float ss = 0.f;
#pragma unroll
    for (int j = 0; j < 3; j++) {
        int e = lane + j * 64;
        float x = resid[base + e] + hidden[base + e];
        loc[j] = x;
        ss += x * x;
    }
#pragma unroll
    for (int off = 32; off > 0; off >>= 1) ss += __shfl_xor(ss, off, 64);
    float scale = rsqrtf(ss * (1.f / (float)E) + 1e-5f);
#pragma unroll
    for (int j = 0; j < 3; j++) {
        int e = lane + j * 64;
        v[e] = loc[j] * scale * norm_f_w[e];
    }
    __syncthreads();
    if (lane < NC) {
        float acc = head_b[lane];
        for (int e = 0; e < E; e++) acc += v[e] * head_w[lane * E + e];
        out[b * NC + lane] = acc;
    }
}

// ---------------------------------------------------------------------------
extern "C" void kernel_launch(void* const* d_in, const int* in_sizes, int n_in,
                              void* d_out, int out_size, void* d_ws, size_t ws_size,
                              hipStream_t stream) {
    const float* imgs      = (const float*)d_in[0];
    const float* patch_w   = (const float*)d_in[1];
    const float* patch_b   = (const float*)d_in[2];
    const float* cls_token = (const float*)d_in[3];
    const float* pos_embed = (const float*)d_in[4];
    const float* cnn_w     = (const float*)d_in[5];
    const float* cnn_b     = (const float*)d_in[6];
    const float* norm_w    = (const float*)d_in[7];
    const float* in_proj_w = (const float*)d_in[8];
    const float* conv_w    = (const float*)d_in[9];
    const float* conv_b    = (const float*)d_in[10];
    const float* x_proj_w  = (const float*)d_in[11];
    const float* dt_proj_w = (const float*)d_in[12];
    const float* dt_proj_b = (const float*)d_in[13];
    const float* A_log     = (const float*)d_in[14];
    const float* Dskip     = (const float*)d_in[15];
    const float* out_proj_w= (const float*)d_in[16];
    const float* norm_f_w  = (const float*)d_in[17];
    const float* head_w    = (const float*)d_in[18];
    const float* head_b    = (const float*)d_in[19];

    float* ws = (float*)d_ws;
    size_t off = 0;
    float* resid  = ws + off; off += (size_t)NTOK * E;
    float* hidden = ws + off; off += (size_t)NTOK * E;
    float* xz     = ws + off; off += (size_t)NTOK * 2 * DI;
    float* xc     = ws + off; off += (size_t)NTOK * DI;
    float* xdb    = ws + off; off += (size_t)NTOK * 44;
    float* dt     = ws + off; off += (size_t)NTOK * DI;
    float* hend   = ws + off; off += (size_t)BATCH * NCH * DI * S;
    float* hinit  = ws + off; off += (size_t)BATCH * NCH * DI * S;
    float* dtsum  = ws + off; off += (size_t)BATCH * NCH * DI;
    // bf16 regions (as ushort); hn/xc_bf/y_bf live ranges are disjoint
    unsigned short* bf_buf = (unsigned short*)(ws + off); off += (size_t)NTOK * DI / 2;
    unsigned short* w_in  = (unsigned short*)(ws + off); off += (size_t)DEPTH * 2 * DI * E / 2;
    unsigned short* w_x   = (unsigned short*)(ws + off); off += (size_t)DEPTH * 44 * DI / 2 + 8;
    unsigned short* w_out = (unsigned short*)(ws + off); off += (size_t)DEPTH * E * DI / 2;

    unsigned short* hn_bf = bf_buf;   // [NTOK, E]
    unsigned short* xc_bf = bf_buf;   // [NTOK, DI]
    unsigned short* y_bf  = bf_buf;   // [NTOK, DI]

    // weight conversion (cheap, every launch)
    {
        int n1 = DEPTH * 2 * DI * E;
        k_cvt<<<(n1 + 255) / 256, 256, 0, stream>>>(in_proj_w, w_in, n1);
        int n2 = DEPTH * 44 * DI;
        k_cvt<<<(n2 + 255) / 256, 256, 0, stream>>>(x_proj_w, w_x, n2);
        int n3 = DEPTH * E * DI;
        k_cvt<<<(n3 + 255) / 256, 256, 0, stream>>>(out_proj_w, w_out, n3);
    }

    // K0: embed
    k_embed<<<(NTOK * E) / 256, 256, 0, stream>>>(imgs, patch_w, patch_b, cls_token,
                                                  pos_embed, cnn_w, cnn_b, resid);

    for (int i = 0; i < DEPTH; i++) {
        if (i == 0)
            k_rmsnorm<false><<<NTOK / 4, 256, 0, stream>>>(hidden, resid, hn_bf, norm_w + i * E);
        else
            k_rmsnorm<true><<<NTOK / 4, 256, 0, stream>>>(hidden, resid, hn_bf, norm_w + i * E);

        // in_proj: [NTOK,192]bf16 x [768,192]bf16^T -> xz f32 [NTOK,768]
        {
            dim3 g((2 * DI) / 64, (NTOK + 127) / 128);
            k_gemm_bf16<<<g, 256, 0, stream>>>(hn_bf, w_in + (size_t)i * 2 * DI * E, xz,
                                               NTOK, 2 * DI, E);
        }
        // causal conv4 + silu -> xc f32 + bf16
        k_conv<<<(NTOK * DI) / 256, 256, 0, stream>>>(xz, conv_w + (size_t)i * DI * 4,
                                                      conv_b + (size_t)i * DI, xc, xc_bf);
        // x_proj: [NTOK,384]bf16 x [44,384]bf16^T -> xdb f32 [NTOK,44]
        {
            dim3 g(1, (NTOK + 127) / 128);
            k_gemm_bf16<<<g, 256, 0, stream>>>(xc_bf, w_x + (size_t)i * 44 * DI, xdb,
                                               NTOK, 44, DI);
        }
        // dt_proj + softplus (elementwise, K=12)
        k_dtproj<<<(NTOK * DI) / 256, 256, 0, stream>>>(xdb, dt_proj_w + (size_t)i * DI * R,
                                                        dt_proj_b + (size_t)i * DI, dt);
        // chunked scan
        {
            dim3 g(NCH, BATCH);
            k_scanA<<<g, DI, 0, stream>>>(dt, xc, xdb, A_log + (size_t)i * DI * S, hend, dtsum);
            k_scanB<<<(BATCH * DI + 255) / 256, 256, 0, stream>>>(
                hend, dtsum, A_log + (size_t)i * DI * S, hinit);
            k_scanC<<<g, DI, 0, stream>>>(xz, xc, xdb, A_log + (size_t)i * DI * S,
                                          Dskip + (size_t)i * DI, hinit, dt, y_bf);
        }
        // out_proj: [NTOK,384]bf16 x [192,384]bf16^T -> hidden f32 [NTOK,192]
        {
            dim3 g(E / 64, (NTOK + 127) / 128);
            k_gemm_bf16<<<g, 256, 0, stream>>>(y_bf, w_out + (size_t)i * E * DI, hidden,
                                               NTOK, E, DI);
        }
    }

    k_head<<<BATCH, 64, 0, stream>>>(resid, hidden, norm_f_w, head_w, head_b, (float*)d_out);
}